// Round 2
// baseline (351.720 us; speedup 1.0000x reference)
//
#include <hip/hip_runtime.h>

#define N_NODES 50000
#define N_EDGES 600000
#define F_NODE 128
#define F_EDGE 32
#define MSG 32
#define NPB 64          // nodes per fused block
#define CHK 128         // edges per chunk (v3: halved -> 6 blocks/CU)
#define QBLOCKS ((N_NODES + NPB - 1) / NPB)        // 782
#define CBLOCKS ((N_EDGES + 255) / 256)            // 2344

// bf16 helpers
__device__ __forceinline__ unsigned short f2bf(float f) {
    union { float f; unsigned int u; } v; v.f = f;
    unsigned int r = v.u + 0x7fffu + ((v.u >> 16) & 1u);
    return (unsigned short)(r >> 16);
}

// Raw barrier: lgkmcnt(0)-only fence + s_barrier (no vmcnt drain ->
// prefetched global loads stay in flight across barriers).
#define BAR_LGKM() do {                                           \
    asm volatile("s_waitcnt lgkmcnt(0)" ::: "memory");            \
    __builtin_amdgcn_s_barrier();                                 \
    asm volatile("" ::: "memory");                                \
} while (0)

// ---------------------------------------------------------------------------
// qcount: blocks [0,QBLOCKS) compute Q[n] = nf[n] @ We[128:256] -> bf16;
// blocks [QBLOCKS,..) do the degree histogram. (proven)
// ---------------------------------------------------------------------------
__global__ __launch_bounds__(256)
void qcount_kernel(const float* __restrict__ nf,
                   const float* __restrict__ We,     // [288][32]
                   const int* __restrict__ idx,      // [2][E]
                   unsigned short* __restrict__ Q,   // [N][32] bf16
                   int* __restrict__ deg)
{
    if (blockIdx.x >= QBLOCKS) {
        int e = (blockIdx.x - QBLOCKS) * 256 + threadIdx.x;
        if (e < N_EDGES) {
            int n = idx[e];
            if ((unsigned)n < (unsigned)N_NODES) atomicAdd(&deg[n], 1);
        }
        return;
    }
    __shared__ float sInT[32 * 64];
    __shared__ float sWeC[32 * 32];

    const int tid = threadIdx.x;
    const int n0b = blockIdx.x * NPB;
    const int ng = tid & 31;
    const int og = tid >> 5;

    float accp[2][4];
#pragma unroll
    for (int i = 0; i < 2; ++i)
#pragma unroll
        for (int j = 0; j < 4; ++j) accp[i][j] = 0.f;

    for (int kc = 0; kc < 4; ++kc) {
        __syncthreads();
        ((float4*)sWeC)[tid] = ((const float4*)(We + (128 + kc * 32) * MSG))[tid];
        {
            int nl = tid >> 2, q = tid & 3;
            int n = n0b + nl; if (n >= N_NODES) n = N_NODES - 1;
            const float4* src4 = (const float4*)(nf + (size_t)n * F_NODE + kc * 32);
#pragma unroll
            for (int h = 0; h < 2; ++h) {
                float4 v = src4[q * 2 + h];
                int kl = q * 8 + h * 4;
                sInT[(kl + 0) * 64 + nl] = v.x;
                sInT[(kl + 1) * 64 + nl] = v.y;
                sInT[(kl + 2) * 64 + nl] = v.z;
                sInT[(kl + 3) * 64 + nl] = v.w;
            }
        }
        __syncthreads();
#pragma unroll
        for (int k = 0; k < 32; ++k) {
            float2 m = *(const float2*)&sInT[k * 64 + 2 * ng];
            float4 w = *(const float4*)&sWeC[k * 32 + og * 4];
            accp[0][0] += m.x * w.x; accp[0][1] += m.x * w.y;
            accp[0][2] += m.x * w.z; accp[0][3] += m.x * w.w;
            accp[1][0] += m.y * w.x; accp[1][1] += m.y * w.y;
            accp[1][2] += m.y * w.z; accp[1][3] += m.y * w.w;
        }
    }
#pragma unroll
    for (int i = 0; i < 2; ++i) {
        int n = n0b + 2 * ng + i;
        if (n < N_NODES) {
            ushort4 o;
            o.x = f2bf(accp[i][0]); o.y = f2bf(accp[i][1]);
            o.z = f2bf(accp[i][2]); o.w = f2bf(accp[i][3]);
            *(ushort4*)(Q + (size_t)n * MSG + og * 4) = o;
        }
    }
}

// ---------------------------------------------------------------------------
// scan v2: coalesced tile loop, 1 block x 1024. (proven last round)
// ---------------------------------------------------------------------------
__global__ __launch_bounds__(1024)
void scan_kernel(int* __restrict__ deg_cursor) {
    __shared__ int wsum[16];
    __shared__ int wpre[16];
    const int t = threadIdx.x;
    const int lane = t & 63;
    const int wid = t >> 6;
    const int NT = (N_NODES + 1023) / 1024;   // 49
    int run = 0;
    int vnext = deg_cursor[t];                 // tile 0 (t < N_NODES always)
    for (int tt = 0; tt < NT; ++tt) {
        int v = vnext;
        if (tt + 1 < NT) {
            int ni = (tt + 1) * 1024 + t;
            vnext = (ni < N_NODES) ? deg_cursor[ni] : 0;
        }
        int x = v;
#pragma unroll
        for (int d = 1; d < 64; d <<= 1) {
            int u = __shfl_up(x, (unsigned)d, 64);
            if (lane >= d) x += u;
        }
        if (lane == 63) wsum[wid] = x;
        BAR_LGKM();
        if (wid == 0) {
            int s = (lane < 16) ? wsum[lane] : 0;
#pragma unroll
            for (int d = 1; d < 16; d <<= 1) {
                int u = __shfl_up(s, (unsigned)d, 64);
                if (lane >= d) s += u;
            }
            if (lane < 16) wpre[lane] = s;
        }
        BAR_LGKM();
        int wexcl = (wid > 0) ? wpre[wid - 1] : 0;
        int total = wpre[15];
        int gi = tt * 1024 + t;
        if (gi < N_NODES) deg_cursor[gi] = run + wexcl + (x - v);
        run += total;
        BAR_LGKM();
    }
}

// ---------------------------------------------------------------------------
// scatter: edge ids into destination-sorted order; cursor[n] -> end offset.
// ---------------------------------------------------------------------------
__global__ void scatter_kernel(const int* __restrict__ idx, int* __restrict__ cursor,
                               int* __restrict__ perm) {
    int e = blockIdx.x * 256 + threadIdx.x;
    if (e < N_EDGES) {
        int n = idx[e];
        if ((unsigned)n >= (unsigned)N_NODES) n = 0;
        int p = atomicAdd(&cursor[n], 1);
        if ((unsigned)p < (unsigned)N_EDGES) perm[p] = e;
    }
}

// ---------------------------------------------------------------------------
// Fused kernel v3 — occupancy push: CHK 256->128, unified LDS block 26384 B
// -> 6 blocks/CU (24 waves, was 12). Pipeline (v2-proven) kept: raw lgkm-only
// barriers, perm 2-deep + ef/n1 1-deep register prefetch, hoisted Q gather,
// XOR bank swizzles re-derived for width 128. Phase-2 sInT overlays the
// then-dead sWeC/sP0h region (sBuf too small to host both). Numerics
// bit-identical to v2 (same accumulation order everywhere).
// LDS map (floats): [0,4096) sBuf | [4096,5120) sWeC | [5120,6400) sP0h(u16)
//                   [6400,6465) sOff | [6465,6593) sNL ((ln<<20)|n1)
// Phase2: sWn = sBuf[0,4096), sInT = [4096,6144) (overlay).
// ---------------------------------------------------------------------------
__global__ __launch_bounds__(256, 6)
void fused_kernel(const float* __restrict__ nf,
                  const int* __restrict__ idx,      // [2][E]
                  const float* __restrict__ ef,     // [E][32]
                  const float* __restrict__ We,     // [288][32]
                  const float* __restrict__ be,     // [32]
                  const float* __restrict__ Wn,     // [160][128]
                  const float* __restrict__ bn,     // [128]
                  const int* __restrict__ perm,     // [E] sorted edge ids
                  const int* __restrict__ cursor,   // [N] end offsets
                  const unsigned short* __restrict__ Q,  // [N][32] bf16
                  float* __restrict__ out)          // [N][128]
{
    __shared__ __align__(16) float S[6596];
    float* sBuf = S;                                  // [32][128] ef^T/msgT
    float* sWeC = S + 4096;                           // [32][32]
    unsigned short* sP0h = (unsigned short*)(S + 5120); // [64][40] bf16
    float* sInT2 = S + 4096;                          // phase2 nfT [32][64]
    int* sOff = (int*)(S + 6400);                     // [65]
    int* sNL  = (int*)(S + 6465);                     // [128] (ln<<20)|n1

    const int tid = threadIdx.x;
    const int n0b = blockIdx.x * NPB;

    if (tid <= NPB) {
        int nn = n0b + tid - 1;
        int v;
        if (nn < 0) v = 0;
        else { if (nn >= N_NODES) nn = N_NODES - 1; v = cursor[nn]; }
        if (v < 0) v = 0;
        if (v > N_EDGES) v = N_EDGES;
        sOff[tid] = v;
    }

    // ================= Phase 0: P0 = nf@We[0:128] + be -> bf16 ============
    {
        float* sInT0 = sBuf;                          // [32][64]
        const int ng = tid & 31, og0 = tid >> 5;
        float accp[2][4];
#pragma unroll
        for (int i = 0; i < 2; ++i)
#pragma unroll
            for (int j = 0; j < 4; ++j) accp[i][j] = 0.f;

        for (int kc = 0; kc < 4; ++kc) {
            __syncthreads();
            ((float4*)sWeC)[tid] = ((const float4*)(We + kc * 32 * MSG))[tid];
            {
                int nl = tid >> 2, q = tid & 3;
                int n = n0b + nl; if (n >= N_NODES) n = N_NODES - 1;
                const float4* src4 = (const float4*)(nf + (size_t)n * F_NODE + kc * 32);
#pragma unroll
                for (int h = 0; h < 2; ++h) {
                    float4 v = src4[q * 2 + h];
                    int kl = q * 8 + h * 4;
                    sInT0[(kl + 0) * 64 + nl] = v.x;
                    sInT0[(kl + 1) * 64 + nl] = v.y;
                    sInT0[(kl + 2) * 64 + nl] = v.z;
                    sInT0[(kl + 3) * 64 + nl] = v.w;
                }
            }
            __syncthreads();
#pragma unroll
            for (int k = 0; k < 32; ++k) {
                float2 m = *(const float2*)&sInT0[k * 64 + 2 * ng];
                float4 w = *(const float4*)&sWeC[k * 32 + og0 * 4];
                accp[0][0] += m.x * w.x; accp[0][1] += m.x * w.y;
                accp[0][2] += m.x * w.z; accp[0][3] += m.x * w.w;
                accp[1][0] += m.y * w.x; accp[1][1] += m.y * w.y;
                accp[1][2] += m.y * w.z; accp[1][3] += m.y * w.w;
            }
        }
#pragma unroll
        for (int i = 0; i < 2; ++i)
#pragma unroll
            for (int j = 0; j < 4; ++j)
                sP0h[(2 * ng + i) * 40 + og0 * 4 + j] =
                    f2bf(accp[i][j] + be[og0 * 4 + j]);
    }

    __syncthreads();                                   // ph0 done with sWeC
    ((float4*)sWeC)[tid] = ((const float4*)(We + 256 * MSG))[tid];  // We_bot

    const int rs = sOff[0];
    const int re = sOff[NPB];

    // persistent per-thread message sums: thread = (node rnl, cols rq8..+7)
    float msum[8];
#pragma unroll
    for (int j = 0; j < 8; ++j) msum[j] = 0.f;
    const int rnl = tid >> 2;
    const int rq8 = (tid & 3) * 8;
    const int rx  = (tid & 3) << 2;      // reduce-phase bank swizzle

    const int eg = tid & 63;   // edges 2*eg, 2*eg+1
    const int og = tid >> 6;   // cols og*8..+7 (wave-uniform)
    const int el = tid >> 1;   // staged edge slot 0..127
    const int h2 = tid & 1;    // which half of the ef row

    // ---- prefetch pipeline registers -------------------------------------
    int n1r = 0;                     // n1 for chunk i (h2==0 lanes)
    int pe_next = 0, pe_next2 = 0;   // perm for chunk i+1 / in flight i+2
    float4 efr[4];                   // my ef half-row for chunk i
#pragma unroll
    for (int q = 0; q < 4; ++q) efr[q] = make_float4(0.f, 0.f, 0.f, 0.f);

    if (rs < re) {
        int e0 = rs + el;
        int pe0 = 0;
        if (e0 < re) {
            pe0 = perm[e0];
            if ((unsigned)pe0 >= (unsigned)N_EDGES) pe0 = 0;   // poison guard
            if (h2 == 0) {
                int tn = idx[N_EDGES + pe0];
                if ((unsigned)tn >= (unsigned)N_NODES) tn = 0;
                n1r = tn;
            }
        }
        const float4* ef4 = (const float4*)(ef + (size_t)pe0 * F_EDGE + h2 * 16);
#pragma unroll
        for (int q = 0; q < 4; ++q) efr[q] = ef4[q];
        int e1 = rs + CHK + el;
        if (e1 < re) {
            int p = perm[e1];
            if ((unsigned)p >= (unsigned)N_EDGES) p = 0;
            pe_next = p;
        }
        pe_next2 = pe_next;          // bootstrap rotation for iter 0
    }

    // ================= Chunk loop =========================================
    for (int cs = rs; cs < re; cs += CHK) {
        BAR_LGKM();        // (A) prev reduction reads done; We_bot visible
        pe_next = pe_next2;
        {
            // ---- consume prefetched ef half-row (k-major, swizzled) ----
#pragma unroll
            for (int q = 0; q < 4; ++q) {
                float4 v = efr[q];
                int g = (h2 * 2 + (q >> 1)) & 3;              // (k>>3)&3 of this quad
                int ctw = ((el & ~3) ^ (g << 2)) + (el & 3);
                int r0 = (h2 * 16 + q * 4) * CHK;
                sBuf[r0 + 0 * CHK + ctw] = v.x;
                sBuf[r0 + 1 * CHK + ctw] = v.y;
                sBuf[r0 + 2 * CHK + ctw] = v.z;
                sBuf[r0 + 3 * CHK + ctw] = v.w;
            }
            // ---- ln (binary search) + packed sNL (h2==0 lanes) ----
            if (h2 == 0) {
                int e = cs + el;
                int ln = 0;
                if (e < re) {
                    int lo = 0, hi = NPB;
#pragma unroll
                    for (int s = 0; s < 6; ++s) {
                        int mid = (lo + hi) >> 1;
                        if (sOff[mid] <= e) lo = mid; else hi = mid;
                    }
                    ln = lo;
                }
                sNL[el] = (ln << 20) | n1r;
            }
            // ---- issue gathers for chunk i+1 ----
            int e1 = cs + CHK + el;
            if (e1 < re) {
                int pe1 = pe_next;
                if (h2 == 0) {
                    int tn = idx[N_EDGES + pe1];
                    if ((unsigned)tn >= (unsigned)N_NODES) tn = 0;
                    n1r = tn;
                }
                const float4* ef4 = (const float4*)(ef + (size_t)pe1 * F_EDGE + h2 * 16);
#pragma unroll
                for (int q = 0; q < 4; ++q) efr[q] = ef4[q];
            } else if (h2 == 0) n1r = 0;
            // ---- issue perm for chunk i+2 ----
            int e2 = cs + 2 * CHK + el;
            if (e2 < re) {
                int p = perm[e2];
                if ((unsigned)p >= (unsigned)N_EDGES) p = 0;
                pe_next2 = p;
            } else pe_next2 = 0;
        }
        BAR_LGKM();        // (B) staging visible

        // Q gather hoisted: in flight during the GEMM below
        int nlv0 = sNL[2 * eg], nlv1 = sNL[2 * eg + 1];
        uint4 qv[2];
        qv[0] = *(const uint4*)(Q + (size_t)(nlv0 & 0xFFFFF) * MSG + og * 8);
        qv[1] = *(const uint4*)(Q + (size_t)(nlv1 & 0xFFFFF) * MSG + og * 8);

        float acc[2][8];
#pragma unroll
        for (int i = 0; i < 2; ++i)
#pragma unroll
            for (int j = 0; j < 8; ++j) acc[i][j] = 0.f;

        const float* weB = sWeC + og * 8;
#pragma unroll
        for (int k = 0; k < 32; ++k) {
            int mb = k * CHK + (((2 * eg) & ~3) ^ (((k >> 3) & 3) << 2)) + ((2 * eg) & 3);
            float2 m = *(const float2*)&sBuf[mb];                 // conflict-free b64
            float4 w0 = *(const float4*)&weB[k * 32];             // broadcast
            float4 w1 = *(const float4*)&weB[k * 32 + 4];
            float ma[2] = { m.x, m.y };
            float wv[8] = { w0.x, w0.y, w0.z, w0.w, w1.x, w1.y, w1.z, w1.w };
#pragma unroll
            for (int i = 0; i < 2; ++i)
#pragma unroll
                for (int j = 0; j < 8; ++j) acc[i][j] += ma[i] * wv[j];
        }

        BAR_LGKM();        // (C) all ef^T reads done; sBuf reusable

        // ---- +P0 +Q, relu, store msgT[col][edge] (b64 along edges) ----
        {
            uint4 pv[2];
            pv[0] = *(const uint4*)((const unsigned short*)sP0h + (nlv0 >> 20) * 40 + og * 8);
            pv[1] = *(const uint4*)((const unsigned short*)sP0h + (nlv1 >> 20) * 40 + og * 8);
            int sb = (((2 * eg) & ~3) ^ (og << 2)) + ((2 * eg) & 3);
#pragma unroll
            for (int j = 0; j < 8; ++j) {
                float sv[2];
#pragma unroll
                for (int i = 0; i < 2; ++i) {
                    unsigned qu = ((const unsigned*)&qv[i])[j >> 1];
                    unsigned pu = ((const unsigned*)&pv[i])[j >> 1];
                    float qf = __uint_as_float((j & 1) ? (qu & 0xffff0000u) : (qu << 16));
                    float pf = __uint_as_float((j & 1) ? (pu & 0xffff0000u) : (pu << 16));
                    sv[i] = fmaxf(acc[i][j] + pf + qf, 0.f);
                }
                float2 s2; s2.x = sv[0]; s2.y = sv[1];
                *(float2*)&sBuf[(og * 8 + j) * CHK + sb] = s2;   // aligned, conflict-free
            }
        }
        BAR_LGKM();        // (D) msgT visible

        // ---- segmented reduction (no atomics): my node's range this chunk
        {
            int lo = sOff[rnl] - cs;     if (lo < 0) lo = 0;
            int hi = sOff[rnl + 1] - cs; if (hi > CHK) hi = CHK;
            for (int elr = lo; elr < hi; ++elr) {
                int ebase = ((elr & ~3) ^ rx) + (elr & 3);
#pragma unroll
                for (int j = 0; j < 8; ++j)
                    msum[j] += sBuf[(rq8 + j) * CHK + ebase];
            }
        }
    }

    // ================= Phase 2: node GEMM (proven; kc=4 from msum) ========
    // sWn = sBuf [32][128]; sInT = sInT2 [32][64] (overlays sWeC/sP0h, dead)
    const int ng  = tid & 31;
    const int og2 = tid >> 5;

    float acc2[2][16];
#pragma unroll
    for (int i = 0; i < 2; ++i)
#pragma unroll
        for (int j = 0; j < 16; ++j) acc2[i][j] = 0.f;

    for (int kc = 0; kc < 5; ++kc) {
        __syncthreads();   // kc=0: last reduction reads done (full drain ok here)
        {
            const float4* w4 = (const float4*)(Wn + (size_t)kc * 32 * 128);
            float4* s4 = (float4*)sBuf;
#pragma unroll
            for (int i = 0; i < 4; ++i) s4[tid + 256 * i] = w4[tid + 256 * i];
        }
        {
            int nl = tid >> 2, q = tid & 3;
            if (kc < 4) {
                int n = n0b + nl; if (n >= N_NODES) n = N_NODES - 1;
                const float4* src4 = (const float4*)(nf + (size_t)n * F_NODE + kc * 32);
#pragma unroll
                for (int h = 0; h < 2; ++h) {
                    float4 v = src4[q * 2 + h];
                    int kl = q * 8 + h * 4;
                    sInT2[(kl + 0) * 64 + nl] = v.x;
                    sInT2[(kl + 1) * 64 + nl] = v.y;
                    sInT2[(kl + 2) * 64 + nl] = v.z;
                    sInT2[(kl + 3) * 64 + nl] = v.w;
                }
            } else {
                // thread (nl, q) owns exactly msum for node nl, cols q*8..+7
#pragma unroll
                for (int h = 0; h < 8; ++h)
                    sInT2[(q * 8 + h) * 64 + nl] = msum[h];
            }
        }
        __syncthreads();

#pragma unroll
        for (int k = 0; k < 32; ++k) {
            float2 m = *(const float2*)&sInT2[k * 64 + 2 * ng];
            const float* wr = &sBuf[k * 128 + og2 * 16];
            float4 w0 = *(const float4*)&wr[0];
            float4 w1 = *(const float4*)&wr[4];
            float4 w2 = *(const float4*)&wr[8];
            float4 w3 = *(const float4*)&wr[12];
            float ma[2] = { m.x, m.y };
            float wv[16] = { w0.x,w0.y,w0.z,w0.w, w1.x,w1.y,w1.z,w1.w,
                             w2.x,w2.y,w2.z,w2.w, w3.x,w3.y,w3.z,w3.w };
#pragma unroll
            for (int i = 0; i < 2; ++i)
#pragma unroll
                for (int j = 0; j < 16; ++j) acc2[i][j] += ma[i] * wv[j];
        }
    }

    float nbias[16];
#pragma unroll
    for (int j = 0; j < 16; ++j) nbias[j] = bn[og2 * 16 + j];

#pragma unroll
    for (int i = 0; i < 2; ++i) {
        int n = n0b + 2 * ng + i;
        if (n < N_NODES) {
            float* dst = out + (size_t)n * F_NODE + og2 * 16;
#pragma unroll
            for (int j = 0; j < 16; j += 4) {
                float4 v;
                v.x = fmaxf(acc2[i][j + 0] + nbias[j + 0], 0.f);
                v.y = fmaxf(acc2[i][j + 1] + nbias[j + 1], 0.f);
                v.z = fmaxf(acc2[i][j + 2] + nbias[j + 2], 0.f);
                v.w = fmaxf(acc2[i][j + 3] + nbias[j + 3], 0.f);
                *(float4*)(dst + j) = v;
            }
        }
    }
}

extern "C" void kernel_launch(void* const* d_in, const int* in_sizes, int n_in,
                              void* d_out, int out_size, void* d_ws, size_t ws_size,
                              hipStream_t stream) {
    const float* nf  = (const float*)d_in[0];
    const int*   idx = (const int*)d_in[1];
    const float* ef  = (const float*)d_in[2];
    const float* We  = (const float*)d_in[3];
    const float* be  = (const float*)d_in[4];
    const float* Wn  = (const float*)d_in[5];
    const float* bn  = (const float*)d_in[6];
    float* out = (float*)d_out;

    // ws: deg 0.2 MB + perm 2.4 MB + Q bf16 3.2 MB = 5.8 MB (confirmed safe)
    int* deg_cursor = (int*)d_ws;                          // 50000
    int* perm       = deg_cursor + N_NODES;                // 600000
    unsigned short* Q = (unsigned short*)(perm + N_EDGES); // [N][32] bf16

    hipMemsetAsync(deg_cursor, 0, (size_t)N_NODES * sizeof(int), stream);

    qcount_kernel<<<QBLOCKS + CBLOCKS, 256, 0, stream>>>(nf, We, idx, Q, deg_cursor);
    scan_kernel<<<1, 1024, 0, stream>>>(deg_cursor);
    scatter_kernel<<<CBLOCKS, 256, 0, stream>>>(idx, deg_cursor, perm);

    fused_kernel<<<QBLOCKS, 256, 0, stream>>>(
        nf, idx, ef, We, be, Wn, bn, perm, deg_cursor, Q, out);
}

// Round 3
// 298.175 us; speedup vs baseline: 1.1796x; 1.1796x over previous
//
#include <hip/hip_runtime.h>

#define N_NODES 50000
#define N_EDGES 600000
#define F_NODE 128
#define F_EDGE 32
#define MSG 32
#define NPB 32          // nodes per fused block (v4: 32 -> 1563 blocks, 6.1/CU)
#define CHK 128         // edges per chunk
#define QB64 ((N_NODES + 63) / 64)                 // 782 (qcount tiling)
#define FBLOCKS ((N_NODES + NPB - 1) / NPB)        // 1563
#define CBLOCKS ((N_EDGES + 255) / 256)            // 2344

// bf16 helpers
__device__ __forceinline__ unsigned short f2bf(float f) {
    union { float f; unsigned int u; } v; v.f = f;
    unsigned int r = v.u + 0x7fffu + ((v.u >> 16) & 1u);
    return (unsigned short)(r >> 16);
}

// Raw barrier: lgkmcnt(0)-only fence + s_barrier (no vmcnt drain ->
// prefetched global loads stay in flight across barriers).
#define BAR_LGKM() do {                                           \
    asm volatile("s_waitcnt lgkmcnt(0)" ::: "memory");            \
    __builtin_amdgcn_s_barrier();                                 \
    asm volatile("" ::: "memory");                                \
} while (0)

// ---------------------------------------------------------------------------
// qcount v2: blocks [0,QB64) compute BOTH halves of the edge-MLP node terms:
//   P0[n] = nf[n] @ We[0:128]  + be  -> bf16   (was fused phase 0)
//   Q [n] = nf[n] @ We[128:256]      -> bf16
// (identical k/kc accumulation order as before -> bit-identical values).
// Blocks [QB64,..) do the degree histogram.
// ---------------------------------------------------------------------------
__global__ __launch_bounds__(256)
void qcount_kernel(const float* __restrict__ nf,
                   const float* __restrict__ We,     // [288][32]
                   const float* __restrict__ be,     // [32]
                   const int* __restrict__ idx,      // [2][E]
                   unsigned short* __restrict__ Q,   // [N][32] bf16
                   unsigned short* __restrict__ P0g, // [N][32] bf16
                   int* __restrict__ deg)
{
    if (blockIdx.x >= QB64) {
        int e = (blockIdx.x - QB64) * 256 + threadIdx.x;
        if (e < N_EDGES) {
            int n = idx[e];
            if ((unsigned)n < (unsigned)N_NODES) atomicAdd(&deg[n], 1);
        }
        return;
    }
    __shared__ float sInT[32 * 64];
    __shared__ float sWeA[32 * 32];   // We top (P0 half)
    __shared__ float sWeB[32 * 32];   // We mid (Q half)

    const int tid = threadIdx.x;
    const int n0b = blockIdx.x * 64;
    const int ng = tid & 31;
    const int og = tid >> 5;

    float accA[2][4], accB[2][4];
#pragma unroll
    for (int i = 0; i < 2; ++i)
#pragma unroll
        for (int j = 0; j < 4; ++j) { accA[i][j] = 0.f; accB[i][j] = 0.f; }

    for (int kc = 0; kc < 4; ++kc) {
        __syncthreads();
        ((float4*)sWeA)[tid] = ((const float4*)(We + kc * 32 * MSG))[tid];
        ((float4*)sWeB)[tid] = ((const float4*)(We + (128 + kc * 32) * MSG))[tid];
        {
            int nl = tid >> 2, q = tid & 3;
            int n = n0b + nl; if (n >= N_NODES) n = N_NODES - 1;
            const float4* src4 = (const float4*)(nf + (size_t)n * F_NODE + kc * 32);
#pragma unroll
            for (int h = 0; h < 2; ++h) {
                float4 v = src4[q * 2 + h];
                int kl = q * 8 + h * 4;
                sInT[(kl + 0) * 64 + nl] = v.x;
                sInT[(kl + 1) * 64 + nl] = v.y;
                sInT[(kl + 2) * 64 + nl] = v.z;
                sInT[(kl + 3) * 64 + nl] = v.w;
            }
        }
        __syncthreads();
#pragma unroll
        for (int k = 0; k < 32; ++k) {
            float2 m = *(const float2*)&sInT[k * 64 + 2 * ng];
            float4 wa = *(const float4*)&sWeA[k * 32 + og * 4];
            float4 wb = *(const float4*)&sWeB[k * 32 + og * 4];
            accA[0][0] += m.x * wa.x; accA[0][1] += m.x * wa.y;
            accA[0][2] += m.x * wa.z; accA[0][3] += m.x * wa.w;
            accA[1][0] += m.y * wa.x; accA[1][1] += m.y * wa.y;
            accA[1][2] += m.y * wa.z; accA[1][3] += m.y * wa.w;
            accB[0][0] += m.x * wb.x; accB[0][1] += m.x * wb.y;
            accB[0][2] += m.x * wb.z; accB[0][3] += m.x * wb.w;
            accB[1][0] += m.y * wb.x; accB[1][1] += m.y * wb.y;
            accB[1][2] += m.y * wb.z; accB[1][3] += m.y * wb.w;
        }
    }
    float bloc[4];
#pragma unroll
    for (int j = 0; j < 4; ++j) bloc[j] = be[og * 4 + j];
#pragma unroll
    for (int i = 0; i < 2; ++i) {
        int n = n0b + 2 * ng + i;
        if (n < N_NODES) {
            ushort4 oq, op;
            oq.x = f2bf(accB[i][0]); oq.y = f2bf(accB[i][1]);
            oq.z = f2bf(accB[i][2]); oq.w = f2bf(accB[i][3]);
            op.x = f2bf(accA[i][0] + bloc[0]); op.y = f2bf(accA[i][1] + bloc[1]);
            op.z = f2bf(accA[i][2] + bloc[2]); op.w = f2bf(accA[i][3] + bloc[3]);
            *(ushort4*)(Q   + (size_t)n * MSG + og * 4) = oq;
            *(ushort4*)(P0g + (size_t)n * MSG + og * 4) = op;
        }
    }
}

// ---------------------------------------------------------------------------
// scan v3: int4 per thread (4096 ints/tile), 13 tiles instead of 49 ->
// 3x fewer barriers + global round-trips on the single-block latency chain.
// N_NODES = 50000 is divisible by 4 -> clean int4 tiling.
// ---------------------------------------------------------------------------
__global__ __launch_bounds__(1024)
void scan_kernel(int* __restrict__ deg_cursor) {
    __shared__ int wsum[16];
    __shared__ int wpre[16];
    const int t = threadIdx.x;
    const int lane = t & 63;
    const int wid = t >> 6;
    const int N4 = N_NODES / 4;              // 12500
    const int NT = (N4 + 1023) / 1024;       // 13
    int run = 0;
    int4 vnext = make_int4(0, 0, 0, 0);
    if (t < N4) vnext = ((const int4*)deg_cursor)[t];
    for (int tt = 0; tt < NT; ++tt) {
        int4 v = vnext;
        if (tt + 1 < NT) {
            int ni = (tt + 1) * 1024 + t;
            vnext = (ni < N4) ? ((const int4*)deg_cursor)[ni] : make_int4(0, 0, 0, 0);
        }
        int s = v.x + v.y + v.z + v.w;
        int x = s;
#pragma unroll
        for (int d = 1; d < 64; d <<= 1) {
            int u = __shfl_up(x, (unsigned)d, 64);
            if (lane >= d) x += u;
        }
        if (lane == 63) wsum[wid] = x;
        BAR_LGKM();
        if (wid == 0) {
            int ss = (lane < 16) ? wsum[lane] : 0;
#pragma unroll
            for (int d = 1; d < 16; d <<= 1) {
                int u = __shfl_up(ss, (unsigned)d, 64);
                if (lane >= d) ss += u;
            }
            if (lane < 16) wpre[lane] = ss;
        }
        BAR_LGKM();
        int wexcl = (wid > 0) ? wpre[wid - 1] : 0;
        int total = wpre[15];
        int i4 = tt * 1024 + t;
        if (i4 < N4) {
            int base = run + wexcl + (x - s);
            int4 o;
            o.x = base;
            o.y = base + v.x;
            o.z = base + v.x + v.y;
            o.w = base + v.x + v.y + v.z;
            ((int4*)deg_cursor)[i4] = o;
        }
        run += total;
        BAR_LGKM();
    }
}

// ---------------------------------------------------------------------------
// scatter: edge ids into destination-sorted order; cursor[n] -> end offset.
// ---------------------------------------------------------------------------
__global__ void scatter_kernel(const int* __restrict__ idx, int* __restrict__ cursor,
                               int* __restrict__ perm) {
    int e = blockIdx.x * 256 + threadIdx.x;
    if (e < N_EDGES) {
        int n = idx[e];
        if ((unsigned)n >= (unsigned)N_NODES) n = 0;
        int p = atomicAdd(&cursor[n], 1);
        if ((unsigned)p < (unsigned)N_EDGES) perm[p] = e;
    }
}

// ---------------------------------------------------------------------------
// Fused kernel v4 — grid-occupancy fix. v3 lesson: grid (782 blocks) was the
// occupancy limiter, and (256,6) caused spills (VGPR 40, WRITE 4x).
//  - NPB=32 -> 1563 blocks (6.1/CU supply); CHK=128 -> LDS ~21 KB;
//    __launch_bounds__(256,5): VGPR cap 102 (est. need ~80, no spill) ->
//    5 blocks/CU co-resident = 20 waves (v2 had 12).
//  - Phase 0 moved to qcount (P0 gathered from global, hoisted w/ Q gather
//    under the GEMM). Pipeline (v2/v3-proven) otherwise unchanged: raw
//    lgkm-only barriers, perm 2-deep + ef/n1 1-deep register prefetch,
//    XOR bank swizzles.
// LDS map (floats): [0,4096) sBuf | [4096,5120) sWeC | ints at [5120..]
// Phase2: sWn = sBuf [32][128]; sInT2 = sWeC region [32][32] XOR-swizzled.
// ---------------------------------------------------------------------------
__global__ __launch_bounds__(256, 5)
void fused_kernel(const float* __restrict__ nf,
                  const int* __restrict__ idx,      // [2][E]
                  const float* __restrict__ ef,     // [E][32]
                  const float* __restrict__ We,     // [288][32]
                  const float* __restrict__ Wn,     // [160][128]
                  const float* __restrict__ bn,     // [128]
                  const int* __restrict__ perm,     // [E] sorted edge ids
                  const int* __restrict__ cursor,   // [N] end offsets
                  const unsigned short* __restrict__ Q,    // [N][32] bf16
                  const unsigned short* __restrict__ P0g,  // [N][32] bf16
                  float* __restrict__ out)          // [N][128]
{
    __shared__ __align__(16) float S[5284];
    float* sBuf = S;                                  // [32][128] ef^T/msgT
    float* sWeC = S + 4096;                           // [32][32] We_bot
    float* sInT2 = S + 4096;                          // phase2 nfT (overlay)
    int* sOff = (int*)(S + 5120);                     // [33]
    int* sNL  = (int*)(S + 5153);                     // [128] (ln<<20)|n1

    const int tid = threadIdx.x;
    const int n0b = blockIdx.x * NPB;

    if (tid <= NPB) {
        int nn = n0b + tid - 1;
        int v;
        if (nn < 0) v = 0;
        else { if (nn >= N_NODES) nn = N_NODES - 1; v = cursor[nn]; }
        if (v < 0) v = 0;
        if (v > N_EDGES) v = N_EDGES;
        sOff[tid] = v;
    }
    ((float4*)sWeC)[tid] = ((const float4*)(We + 256 * MSG))[tid];  // We_bot
    __syncthreads();

    const int rs = sOff[0];
    const int re = sOff[NPB];

    // persistent per-thread message sums: thread = (node rnl, cols rq4..+3)
    float msum[4];
#pragma unroll
    for (int j = 0; j < 4; ++j) msum[j] = 0.f;
    const int rnl = tid >> 3;            // node 0..31
    const int rq4 = (tid & 7) * 4;       // col group
    const int gx  = (rq4 >> 3) << 2;     // reduce-phase swizzle (matches store)

    const int eg = tid & 63;   // edges 2*eg, 2*eg+1
    const int og = tid >> 6;   // cols og*8..+7 (wave-uniform)
    const int el = tid >> 1;   // staged edge slot 0..127
    const int h2 = tid & 1;    // which half of the ef row

    // ---- prefetch pipeline registers -------------------------------------
    int n1r = 0;                     // n1 for chunk i (h2==0 lanes)
    int pe_next = 0, pe_next2 = 0;   // perm for chunk i+1 / in flight i+2
    float4 efr[4];                   // my ef half-row for chunk i
#pragma unroll
    for (int q = 0; q < 4; ++q) efr[q] = make_float4(0.f, 0.f, 0.f, 0.f);

    if (rs < re) {
        int e0 = rs + el;
        int pe0 = 0;
        if (e0 < re) {
            pe0 = perm[e0];
            if ((unsigned)pe0 >= (unsigned)N_EDGES) pe0 = 0;   // poison guard
            if (h2 == 0) {
                int tn = idx[N_EDGES + pe0];
                if ((unsigned)tn >= (unsigned)N_NODES) tn = 0;
                n1r = tn;
            }
        }
        const float4* ef4 = (const float4*)(ef + (size_t)pe0 * F_EDGE + h2 * 16);
#pragma unroll
        for (int q = 0; q < 4; ++q) efr[q] = ef4[q];
        int e1 = rs + CHK + el;
        if (e1 < re) {
            int p = perm[e1];
            if ((unsigned)p >= (unsigned)N_EDGES) p = 0;
            pe_next = p;
        }
        pe_next2 = pe_next;          // bootstrap rotation for iter 0
    }

    // ================= Chunk loop =========================================
    for (int cs = rs; cs < re; cs += CHK) {
        BAR_LGKM();        // (A) prev reduction reads done
        pe_next = pe_next2;
        {
            // ---- consume prefetched ef half-row (k-major, swizzled) ----
#pragma unroll
            for (int q = 0; q < 4; ++q) {
                float4 v = efr[q];
                int g = (h2 * 2 + (q >> 1)) & 3;              // (k>>3)&3 of this quad
                int ctw = ((el & ~3) ^ (g << 2)) + (el & 3);
                int r0 = (h2 * 16 + q * 4) * CHK;
                sBuf[r0 + 0 * CHK + ctw] = v.x;
                sBuf[r0 + 1 * CHK + ctw] = v.y;
                sBuf[r0 + 2 * CHK + ctw] = v.z;
                sBuf[r0 + 3 * CHK + ctw] = v.w;
            }
            // ---- ln (binary search over sOff[0..32]) + packed sNL ----
            if (h2 == 0) {
                int e = cs + el;
                int ln = 0;
                if (e < re) {
                    int lo = 0, hi = NPB;
#pragma unroll
                    for (int s = 0; s < 5; ++s) {
                        int mid = (lo + hi) >> 1;
                        if (sOff[mid] <= e) lo = mid; else hi = mid;
                    }
                    ln = lo;
                }
                sNL[el] = (ln << 20) | n1r;
            }
            // ---- issue gathers for chunk i+1 ----
            int e1 = cs + CHK + el;
            if (e1 < re) {
                int pe1 = pe_next;
                if (h2 == 0) {
                    int tn = idx[N_EDGES + pe1];
                    if ((unsigned)tn >= (unsigned)N_NODES) tn = 0;
                    n1r = tn;
                }
                const float4* ef4 = (const float4*)(ef + (size_t)pe1 * F_EDGE + h2 * 16);
#pragma unroll
                for (int q = 0; q < 4; ++q) efr[q] = ef4[q];
            } else if (h2 == 0) n1r = 0;
            // ---- issue perm for chunk i+2 ----
            int e2 = cs + 2 * CHK + el;
            if (e2 < re) {
                int p = perm[e2];
                if ((unsigned)p >= (unsigned)N_EDGES) p = 0;
                pe_next2 = p;
            } else pe_next2 = 0;
        }
        BAR_LGKM();        // (B) staging visible

        // Q + P0 gathers hoisted: in flight during the GEMM below
        int nlv0 = sNL[2 * eg], nlv1 = sNL[2 * eg + 1];
        uint4 qv[2], pv[2];
        qv[0] = *(const uint4*)(Q   + (size_t)(nlv0 & 0xFFFFF) * MSG + og * 8);
        qv[1] = *(const uint4*)(Q   + (size_t)(nlv1 & 0xFFFFF) * MSG + og * 8);
        pv[0] = *(const uint4*)(P0g + (size_t)(n0b + (nlv0 >> 20)) * MSG + og * 8);
        pv[1] = *(const uint4*)(P0g + (size_t)(n0b + (nlv1 >> 20)) * MSG + og * 8);

        float acc[2][8];
#pragma unroll
        for (int i = 0; i < 2; ++i)
#pragma unroll
            for (int j = 0; j < 8; ++j) acc[i][j] = 0.f;

        const float* weB = sWeC + og * 8;
#pragma unroll
        for (int k = 0; k < 32; ++k) {
            int mb = k * CHK + (((2 * eg) & ~3) ^ (((k >> 3) & 3) << 2)) + ((2 * eg) & 3);
            float2 m = *(const float2*)&sBuf[mb];
            float4 w0 = *(const float4*)&weB[k * 32];             // broadcast
            float4 w1 = *(const float4*)&weB[k * 32 + 4];
            float ma[2] = { m.x, m.y };
            float wv[8] = { w0.x, w0.y, w0.z, w0.w, w1.x, w1.y, w1.z, w1.w };
#pragma unroll
            for (int i = 0; i < 2; ++i)
#pragma unroll
                for (int j = 0; j < 8; ++j) acc[i][j] += ma[i] * wv[j];
        }

        BAR_LGKM();        // (C) all ef^T reads done; sBuf reusable

        // ---- +P0 +Q, relu, store msgT[col][edge] (b64 along edges) ----
        {
            int sb = (((2 * eg) & ~3) ^ (og << 2)) + ((2 * eg) & 3);
#pragma unroll
            for (int j = 0; j < 8; ++j) {
                float sv[2];
#pragma unroll
                for (int i = 0; i < 2; ++i) {
                    unsigned qu = ((const unsigned*)&qv[i])[j >> 1];
                    unsigned pu = ((const unsigned*)&pv[i])[j >> 1];
                    float qf = __uint_as_float((j & 1) ? (qu & 0xffff0000u) : (qu << 16));
                    float pf = __uint_as_float((j & 1) ? (pu & 0xffff0000u) : (pu << 16));
                    sv[i] = fmaxf(acc[i][j] + pf + qf, 0.f);
                }
                float2 s2; s2.x = sv[0]; s2.y = sv[1];
                *(float2*)&sBuf[(og * 8 + j) * CHK + sb] = s2;
            }
        }
        BAR_LGKM();        // (D) msgT visible

        // ---- segmented reduction (no atomics): my node's range this chunk
        {
            int lo = sOff[rnl] - cs;     if (lo < 0) lo = 0;
            int hi = sOff[rnl + 1] - cs; if (hi > CHK) hi = CHK;
            for (int elr = lo; elr < hi; ++elr) {
                int ebase = ((elr & ~3) ^ gx) + (elr & 3);
#pragma unroll
                for (int j = 0; j < 4; ++j)
                    msum[j] += sBuf[(rq4 + j) * CHK + ebase];
            }
        }
    }

    // ================= Phase 2: node GEMM, 32 nodes ======================
    // thread = (node ng2 = tid&31, cols og2*16..+15); m scalar per k.
    const int ng2 = tid & 31;
    const int og2 = tid >> 5;

    float acc2[16];
#pragma unroll
    for (int j = 0; j < 16; ++j) acc2[j] = 0.f;

    for (int kc = 0; kc < 5; ++kc) {
        __syncthreads();   // kc=0: last reduction reads done (full drain ok)
        {
            const float4* w4 = (const float4*)(Wn + (size_t)kc * 32 * 128);
            float4* s4 = (float4*)sBuf;
#pragma unroll
            for (int i = 0; i < 4; ++i) s4[tid + 256 * i] = w4[tid + 256 * i];
        }
        {
            if (kc < 4) {
                int nl = tid >> 3, q = tid & 7;
                int n = n0b + nl; if (n >= N_NODES) n = N_NODES - 1;
                float4 v = *(const float4*)(nf + (size_t)n * F_NODE + kc * 32 + q * 4);
#pragma unroll
                for (int h = 0; h < 4; ++h) {
                    int r = q * 4 + h;
                    sInT2[r * 32 + (nl ^ ((r & 7) << 2))] = (&v.x)[h];
                }
            } else {
                // thread (rnl, rq4) owns exactly msum for node rnl, cols rq4..+3
#pragma unroll
                for (int h = 0; h < 4; ++h) {
                    int r = rq4 + h;
                    sInT2[r * 32 + (rnl ^ ((r & 7) << 2))] = msum[h];
                }
            }
        }
        __syncthreads();

#pragma unroll
        for (int k = 0; k < 32; ++k) {
            float m = sInT2[k * 32 + (ng2 ^ ((k & 7) << 2))];
            const float* wr = &sBuf[k * 128 + og2 * 16];
            float4 w0 = *(const float4*)&wr[0];
            float4 w1 = *(const float4*)&wr[4];
            float4 w2 = *(const float4*)&wr[8];
            float4 w3 = *(const float4*)&wr[12];
            float wv[16] = { w0.x,w0.y,w0.z,w0.w, w1.x,w1.y,w1.z,w1.w,
                             w2.x,w2.y,w2.z,w2.w, w3.x,w3.y,w3.z,w3.w };
#pragma unroll
            for (int j = 0; j < 16; ++j) acc2[j] += m * wv[j];
        }
    }

    {
        int n = n0b + ng2;
        if (n < N_NODES) {
            float* dst = out + (size_t)n * F_NODE + og2 * 16;
#pragma unroll
            for (int j = 0; j < 16; j += 4) {
                float4 v;
                v.x = fmaxf(acc2[j + 0] + bn[og2 * 16 + j + 0], 0.f);
                v.y = fmaxf(acc2[j + 1] + bn[og2 * 16 + j + 1], 0.f);
                v.z = fmaxf(acc2[j + 2] + bn[og2 * 16 + j + 2], 0.f);
                v.w = fmaxf(acc2[j + 3] + bn[og2 * 16 + j + 3], 0.f);
                *(float4*)(dst + j) = v;
            }
        }
    }
}

extern "C" void kernel_launch(void* const* d_in, const int* in_sizes, int n_in,
                              void* d_out, int out_size, void* d_ws, size_t ws_size,
                              hipStream_t stream) {
    const float* nf  = (const float*)d_in[0];
    const int*   idx = (const int*)d_in[1];
    const float* ef  = (const float*)d_in[2];
    const float* We  = (const float*)d_in[3];
    const float* be  = (const float*)d_in[4];
    const float* Wn  = (const float*)d_in[5];
    const float* bn  = (const float*)d_in[6];
    float* out = (float*)d_out;

    // ws: deg 0.2 MB + perm 2.4 MB + Q 3.2 MB + P0 3.2 MB = 9.0 MB
    int* deg_cursor = (int*)d_ws;                          // 50000
    int* perm       = deg_cursor + N_NODES;                // 600000
    unsigned short* Q   = (unsigned short*)(perm + N_EDGES);   // [N][32] bf16
    unsigned short* P0g = Q + (size_t)N_NODES * MSG;           // [N][32] bf16

    hipMemsetAsync(deg_cursor, 0, (size_t)N_NODES * sizeof(int), stream);

    qcount_kernel<<<QB64 + CBLOCKS, 256, 0, stream>>>(nf, We, be, idx, Q, P0g, deg_cursor);
    scan_kernel<<<1, 1024, 0, stream>>>(deg_cursor);
    scatter_kernel<<<CBLOCKS, 256, 0, stream>>>(idx, deg_cursor, perm);

    fused_kernel<<<FBLOCKS, 256, 0, stream>>>(
        nf, idx, ef, We, Wn, bn, perm, deg_cursor, Q, P0g, out);
}

// Round 5
// 271.933 us; speedup vs baseline: 1.2934x; 1.0965x over previous
//
#include <hip/hip_runtime.h>

#define N_NODES 50000
#define N_EDGES 600000
#define F_NODE 128
#define F_EDGE 32
#define MSG 32
#define NPB 32          // nodes per fused block -> 1563 blocks (6.1/CU)
#define CHK 128         // edges per chunk
#define QB64 ((N_NODES + 63) / 64)                 // 782 (hist GEMM tiles)
#define FBLOCKS ((N_NODES + NPB - 1) / NPB)        // 1563
#define CBLOCKS ((N_EDGES + 255) / 256)            // 2344

typedef float v2f __attribute__((ext_vector_type(2)));   // -> v_pk_fma_f32

// bf16 helpers
__device__ __forceinline__ unsigned short f2bf(float f) {
    union { float f; unsigned int u; } v; v.f = f;
    unsigned int r = v.u + 0x7fffu + ((v.u >> 16) & 1u);
    return (unsigned short)(r >> 16);
}

// Raw barrier: lgkmcnt(0)-only fence + s_barrier (no vmcnt drain ->
// prefetched global loads stay in flight across barriers).
#define BAR_LGKM() do {                                           \
    asm volatile("s_waitcnt lgkmcnt(0)" ::: "memory");            \
    __builtin_amdgcn_s_barrier();                                 \
    asm volatile("" ::: "memory");                                \
} while (0)

// ---------------------------------------------------------------------------
// hist_kernel: blocks [0,QB64) compute the dual node-term GEMM:
//   P0[n] = nf[n] @ We[0:128] + be -> bf16,  Q[n] = nf[n] @ We[128:256] -> bf16
// Blocks [QB64,..): degree histogram WITH RANK CAPTURE (rank[e] = old count)
// so the later placement needs no atomics. (v5 coop version reverted: the
// cooperative launch silently failed under the harness; logic kept, split
// back into stream-ordered dispatches.)
// ---------------------------------------------------------------------------
__global__ __launch_bounds__(256)
void hist_kernel(const float* __restrict__ nf,
                 const float* __restrict__ We,     // [288][32]
                 const float* __restrict__ be,     // [32]
                 const int* __restrict__ idx,      // [2][E]
                 unsigned short* __restrict__ Q,   // [N][32] bf16
                 unsigned short* __restrict__ P0g, // [N][32] bf16
                 int* __restrict__ deg,            // [N] counts
                 int* __restrict__ rank)           // [E]
{
    if (blockIdx.x >= QB64) {
        int e = (blockIdx.x - QB64) * 256 + threadIdx.x;
        if (e < N_EDGES) {
            int n = idx[e];
            if ((unsigned)n >= (unsigned)N_NODES) n = 0;
            rank[e] = atomicAdd(&deg[n], 1);
        }
        return;
    }
    __shared__ float sInT[32 * 64];
    __shared__ float sWeA[32 * 32];   // We top (P0 half)
    __shared__ float sWeB[32 * 32];   // We mid (Q half)

    const int tid = threadIdx.x;
    const int n0b = blockIdx.x * 64;
    const int ng = tid & 31;
    const int og = tid >> 5;

    v2f accA[4], accB[4];
#pragma unroll
    for (int j = 0; j < 4; ++j) { accA[j] = (v2f){0.f, 0.f}; accB[j] = (v2f){0.f, 0.f}; }

    for (int kc = 0; kc < 4; ++kc) {
        __syncthreads();
        ((float4*)sWeA)[tid] = ((const float4*)(We + kc * 32 * MSG))[tid];
        ((float4*)sWeB)[tid] = ((const float4*)(We + (128 + kc * 32) * MSG))[tid];
        {
            int nl = tid >> 2, q = tid & 3;
            int n = n0b + nl; if (n >= N_NODES) n = N_NODES - 1;
            const float4* src4 = (const float4*)(nf + (size_t)n * F_NODE + kc * 32);
#pragma unroll
            for (int h = 0; h < 2; ++h) {
                float4 v = src4[q * 2 + h];
                int kl = q * 8 + h * 4;
                sInT[(kl + 0) * 64 + nl] = v.x;
                sInT[(kl + 1) * 64 + nl] = v.y;
                sInT[(kl + 2) * 64 + nl] = v.z;
                sInT[(kl + 3) * 64 + nl] = v.w;
            }
        }
        __syncthreads();
#pragma unroll
        for (int k = 0; k < 32; ++k) {
            v2f m = *(const v2f*)&sInT[k * 64 + 2 * ng];
            float4 wa = *(const float4*)&sWeA[k * 32 + og * 4];
            float4 wb = *(const float4*)&sWeB[k * 32 + og * 4];
            accA[0] += m * wa.x; accA[1] += m * wa.y;
            accA[2] += m * wa.z; accA[3] += m * wa.w;
            accB[0] += m * wb.x; accB[1] += m * wb.y;
            accB[2] += m * wb.z; accB[3] += m * wb.w;
        }
    }
    float bloc[4];
#pragma unroll
    for (int j = 0; j < 4; ++j) bloc[j] = be[og * 4 + j];
#pragma unroll
    for (int i = 0; i < 2; ++i) {
        int n = n0b + 2 * ng + i;
        if (n < N_NODES) {
            ushort4 oq, op;
            oq.x = f2bf(accB[0][i]); oq.y = f2bf(accB[1][i]);
            oq.z = f2bf(accB[2][i]); oq.w = f2bf(accB[3][i]);
            op.x = f2bf(accA[0][i] + bloc[0]); op.y = f2bf(accA[1][i] + bloc[1]);
            op.z = f2bf(accA[2][i] + bloc[2]); op.w = f2bf(accA[3][i] + bloc[3]);
            *(ushort4*)(Q   + (size_t)n * MSG + og * 4) = oq;
            *(ushort4*)(P0g + (size_t)n * MSG + og * 4) = op;
        }
    }
}

// ---------------------------------------------------------------------------
// scan v3 (round-3 proven): int4 per thread, 13 tiles, in-place exclusive
// scan: deg (counts) -> start offsets.
// ---------------------------------------------------------------------------
__global__ __launch_bounds__(1024)
void scan_kernel(int* __restrict__ deg_cursor) {
    __shared__ int wsum[16];
    __shared__ int wpre[16];
    const int t = threadIdx.x;
    const int lane = t & 63;
    const int wid = t >> 6;
    const int N4 = N_NODES / 4;              // 12500
    const int NT = (N4 + 1023) / 1024;       // 13
    int run = 0;
    int4 vnext = make_int4(0, 0, 0, 0);
    if (t < N4) vnext = ((const int4*)deg_cursor)[t];
    for (int tt = 0; tt < NT; ++tt) {
        int4 v = vnext;
        if (tt + 1 < NT) {
            int ni = (tt + 1) * 1024 + t;
            vnext = (ni < N4) ? ((const int4*)deg_cursor)[ni] : make_int4(0, 0, 0, 0);
        }
        int s = v.x + v.y + v.z + v.w;
        int x = s;
#pragma unroll
        for (int d = 1; d < 64; d <<= 1) {
            int u = __shfl_up(x, (unsigned)d, 64);
            if (lane >= d) x += u;
        }
        if (lane == 63) wsum[wid] = x;
        BAR_LGKM();
        if (wid == 0) {
            int ss = (lane < 16) ? wsum[lane] : 0;
#pragma unroll
            for (int d = 1; d < 16; d <<= 1) {
                int u = __shfl_up(ss, (unsigned)d, 64);
                if (lane >= d) ss += u;
            }
            if (lane < 16) wpre[lane] = ss;
        }
        BAR_LGKM();
        int wexcl = (wid > 0) ? wpre[wid - 1] : 0;
        int total = wpre[15];
        int i4 = tt * 1024 + t;
        if (i4 < N4) {
            int base = run + wexcl + (x - s);
            int4 o;
            o.x = base;
            o.y = base + v.x;
            o.z = base + v.x + v.y;
            o.w = base + v.x + v.y + v.z;
            ((int4*)deg_cursor)[i4] = o;
        }
        run += total;
        BAR_LGKM();
    }
}

// ---------------------------------------------------------------------------
// place: perm[start[n] + rank[e]] = e — NO atomics (rank captured in hist).
// deg stays = start offsets (fused reads it directly).
// ---------------------------------------------------------------------------
__global__ void place_kernel(const int* __restrict__ idx,
                             const int* __restrict__ startArr,
                             const int* __restrict__ rank,
                             int* __restrict__ perm) {
    int e = blockIdx.x * 256 + threadIdx.x;
    if (e < N_EDGES) {
        int n = idx[e];
        if ((unsigned)n >= (unsigned)N_NODES) n = 0;
        int p = startArr[n] + rank[e];
        if ((unsigned)p < (unsigned)N_EDGES) perm[p] = e;
    }
}

// ---------------------------------------------------------------------------
// Fused kernel v5 (unchanged from last round — audited clean; numerically
// equivalent to v4 which passed):
//  - sP0h in LDS (2 KB, block-local coalesced load) -> only Q gather hoisted.
//  - __launch_bounds__(256,4): VGPR cap 128 (v4's cap-102 spilled).
//  - pk-fma (v2f) GEMMs, bit-identical accumulation order.
//  - startArr holds START offsets: sOff[i] = start[n0b+i].
// LDS ~23.2 KB; 4 blocks/CU (grid supplies 6.1).
// ---------------------------------------------------------------------------
__global__ __launch_bounds__(256, 4)
void fused_kernel(const float* __restrict__ nf,
                  const int* __restrict__ idx,      // [2][E]
                  const float* __restrict__ ef,     // [E][32]
                  const float* __restrict__ We,     // [288][32]
                  const float* __restrict__ Wn,     // [160][128]
                  const float* __restrict__ bn,     // [128]
                  const int* __restrict__ perm,     // [E] sorted edge ids
                  const int* __restrict__ startArr, // [N] start offsets
                  const unsigned short* __restrict__ Q,    // [N][32] bf16
                  const unsigned short* __restrict__ P0g,  // [N][32] bf16
                  float* __restrict__ out)          // [N][128]
{
    __shared__ __align__(16) float S[5796];
    float* sBuf = S;                                  // [32][128] ef^T/msgT
    float* sWeC = S + 4096;                           // [32][32] We_bot
    float* sInT2 = S + 4096;                          // phase2 nfT (overlay)
    unsigned short* sP0h = (unsigned short*)(S + 5120); // [32][32] bf16
    int* sOff = (int*)(S + 5632);                     // [33]
    int* sNL  = (int*)(S + 5665);                     // [128] (ln<<20)|n1

    const int tid = threadIdx.x;
    const int n0b = blockIdx.x * NPB;

    if (tid <= NPB) {
        int nn = n0b + tid;
        int v = (nn < N_NODES) ? startArr[nn] : N_EDGES;
        if (v < 0) v = 0;
        if (v > N_EDGES) v = N_EDGES;
        sOff[tid] = v;
    }
    ((float4*)sWeC)[tid] = ((const float4*)(We + 256 * MSG))[tid];  // We_bot
    if (tid < 128) {   // P0 rows for this block's 32 nodes (2 KB coalesced)
        int r = tid >> 2, c = (tid & 3) * 8;
        int n = n0b + r; if (n >= N_NODES) n = N_NODES - 1;
        *(uint4*)(sP0h + r * MSG + c) = *(const uint4*)(P0g + (size_t)n * MSG + c);
    }
    __syncthreads();

    const int rs = sOff[0];
    const int re = sOff[NPB];

    // persistent per-thread message sums: thread = (node rnl, cols rq4..+3)
    float msum[4];
#pragma unroll
    for (int j = 0; j < 4; ++j) msum[j] = 0.f;
    const int rnl = tid >> 3;            // node 0..31
    const int rq4 = (tid & 7) * 4;       // col group
    const int gx  = (rq4 >> 3) << 2;     // reduce-phase swizzle (matches store)

    const int eg = tid & 63;   // edges 2*eg, 2*eg+1
    const int og = tid >> 6;   // cols og*8..+7 (wave-uniform)
    const int el = tid >> 1;   // staged edge slot 0..127
    const int h2 = tid & 1;    // which half of the ef row

    // ---- prefetch pipeline registers -------------------------------------
    int n1r = 0;                     // n1 for chunk i (h2==0 lanes)
    int pe_next = 0, pe_next2 = 0;   // perm for chunk i+1 / in flight i+2
    float4 efr[4];                   // my ef half-row for chunk i
#pragma unroll
    for (int q = 0; q < 4; ++q) efr[q] = make_float4(0.f, 0.f, 0.f, 0.f);

    if (rs < re) {
        int e0 = rs + el;
        int pe0 = 0;
        if (e0 < re) {
            pe0 = perm[e0];
            if ((unsigned)pe0 >= (unsigned)N_EDGES) pe0 = 0;   // poison guard
            if (h2 == 0) {
                int tn = idx[N_EDGES + pe0];
                if ((unsigned)tn >= (unsigned)N_NODES) tn = 0;
                n1r = tn;
            }
        }
        const float4* ef4 = (const float4*)(ef + (size_t)pe0 * F_EDGE + h2 * 16);
#pragma unroll
        for (int q = 0; q < 4; ++q) efr[q] = ef4[q];
        int e1 = rs + CHK + el;
        if (e1 < re) {
            int p = perm[e1];
            if ((unsigned)p >= (unsigned)N_EDGES) p = 0;
            pe_next = p;
        }
        pe_next2 = pe_next;          // bootstrap rotation for iter 0
    }

    // ================= Chunk loop =========================================
    for (int cs = rs; cs < re; cs += CHK) {
        BAR_LGKM();        // (A) prev reduction reads done
        pe_next = pe_next2;
        {
            // ---- consume prefetched ef half-row (k-major, swizzled) ----
#pragma unroll
            for (int q = 0; q < 4; ++q) {
                float4 v = efr[q];
                int g = (h2 * 2 + (q >> 1)) & 3;              // (k>>3)&3 of this quad
                int ctw = ((el & ~3) ^ (g << 2)) + (el & 3);
                int r0 = (h2 * 16 + q * 4) * CHK;
                sBuf[r0 + 0 * CHK + ctw] = v.x;
                sBuf[r0 + 1 * CHK + ctw] = v.y;
                sBuf[r0 + 2 * CHK + ctw] = v.z;
                sBuf[r0 + 3 * CHK + ctw] = v.w;
            }
            // ---- ln (binary search over sOff[0..32]) + packed sNL ----
            if (h2 == 0) {
                int e = cs + el;
                int ln = 0;
                if (e < re) {
                    int lo = 0, hi = NPB;
#pragma unroll
                    for (int s = 0; s < 5; ++s) {
                        int mid = (lo + hi) >> 1;
                        if (sOff[mid] <= e) lo = mid; else hi = mid;
                    }
                    ln = lo;
                }
                sNL[el] = (ln << 20) | n1r;
            }
            // ---- issue gathers for chunk i+1 ----
            int e1 = cs + CHK + el;
            if (e1 < re) {
                int pe1 = pe_next;
                if (h2 == 0) {
                    int tn = idx[N_EDGES + pe1];
                    if ((unsigned)tn >= (unsigned)N_NODES) tn = 0;
                    n1r = tn;
                }
                const float4* ef4 = (const float4*)(ef + (size_t)pe1 * F_EDGE + h2 * 16);
#pragma unroll
                for (int q = 0; q < 4; ++q) efr[q] = ef4[q];
            } else if (h2 == 0) n1r = 0;
            // ---- issue perm for chunk i+2 ----
            int e2 = cs + 2 * CHK + el;
            if (e2 < re) {
                int p = perm[e2];
                if ((unsigned)p >= (unsigned)N_EDGES) p = 0;
                pe_next2 = p;
            } else pe_next2 = 0;
        }
        BAR_LGKM();        // (B) staging visible

        // Q gather hoisted: in flight during the GEMM below
        int nlv0 = sNL[2 * eg], nlv1 = sNL[2 * eg + 1];
        uint4 qv[2];
        qv[0] = *(const uint4*)(Q + (size_t)(nlv0 & 0xFFFFF) * MSG + og * 8);
        qv[1] = *(const uint4*)(Q + (size_t)(nlv1 & 0xFFFFF) * MSG + og * 8);

        v2f accv[8];                       // (edge0, edge1) per col
#pragma unroll
        for (int j = 0; j < 8; ++j) accv[j] = (v2f){0.f, 0.f};

        const float* weB = sWeC + og * 8;
#pragma unroll
        for (int k = 0; k < 32; ++k) {
            int mb = k * CHK + (((2 * eg) & ~3) ^ (((k >> 3) & 3) << 2)) + ((2 * eg) & 3);
            v2f m = *(const v2f*)&sBuf[mb];
            float4 w0 = *(const float4*)&weB[k * 32];             // broadcast
            float4 w1 = *(const float4*)&weB[k * 32 + 4];
            accv[0] += m * w0.x; accv[1] += m * w0.y;
            accv[2] += m * w0.z; accv[3] += m * w0.w;
            accv[4] += m * w1.x; accv[5] += m * w1.y;
            accv[6] += m * w1.z; accv[7] += m * w1.w;
        }

        BAR_LGKM();        // (C) all ef^T reads done; sBuf reusable

        // ---- +P0 +Q, relu, store msgT[col][edge] (b64 along edges) ----
        {
            uint4 pv[2];
            pv[0] = *(const uint4*)(sP0h + (nlv0 >> 20) * MSG + og * 8);
            pv[1] = *(const uint4*)(sP0h + (nlv1 >> 20) * MSG + og * 8);
            int sb = (((2 * eg) & ~3) ^ (og << 2)) + ((2 * eg) & 3);
#pragma unroll
            for (int j = 0; j < 8; ++j) {
                float sv[2];
#pragma unroll
                for (int i = 0; i < 2; ++i) {
                    unsigned qu = ((const unsigned*)&qv[i])[j >> 1];
                    unsigned pu = ((const unsigned*)&pv[i])[j >> 1];
                    float qf = __uint_as_float((j & 1) ? (qu & 0xffff0000u) : (qu << 16));
                    float pf = __uint_as_float((j & 1) ? (pu & 0xffff0000u) : (pu << 16));
                    sv[i] = fmaxf(accv[j][i] + pf + qf, 0.f);
                }
                float2 s2; s2.x = sv[0]; s2.y = sv[1];
                *(float2*)&sBuf[(og * 8 + j) * CHK + sb] = s2;
            }
        }
        BAR_LGKM();        // (D) msgT visible

        // ---- segmented reduction (no atomics): my node's range this chunk
        {
            int lo = sOff[rnl] - cs;     if (lo < 0) lo = 0;
            int hi = sOff[rnl + 1] - cs; if (hi > CHK) hi = CHK;
            for (int elr = lo; elr < hi; ++elr) {
                int ebase = ((elr & ~3) ^ gx) + (elr & 3);
#pragma unroll
                for (int j = 0; j < 4; ++j)
                    msum[j] += sBuf[(rq4 + j) * CHK + ebase];
            }
        }
    }

    // ================= Phase 2: node GEMM, 32 nodes ======================
    // thread = (node ng2 = tid&31, cols og2*16..+15); m scalar per k.
    const int ng2 = tid & 31;
    const int og2 = tid >> 5;

    v2f acc2v[8];
#pragma unroll
    for (int j = 0; j < 8; ++j) acc2v[j] = (v2f){0.f, 0.f};

    for (int kc = 0; kc < 5; ++kc) {
        __syncthreads();   // kc=0: last reduction reads done (full drain ok)
        {
            const float4* w4 = (const float4*)(Wn + (size_t)kc * 32 * 128);
            float4* s4 = (float4*)sBuf;
#pragma unroll
            for (int i = 0; i < 4; ++i) s4[tid + 256 * i] = w4[tid + 256 * i];
        }
        {
            if (kc < 4) {
                int nl = tid >> 3, q = tid & 7;
                int n = n0b + nl; if (n >= N_NODES) n = N_NODES - 1;
                float4 v = *(const float4*)(nf + (size_t)n * F_NODE + kc * 32 + q * 4);
#pragma unroll
                for (int h = 0; h < 4; ++h) {
                    int r = q * 4 + h;
                    sInT2[r * 32 + (nl ^ ((r & 7) << 2))] = (&v.x)[h];
                }
            } else {
                // thread (rnl, rq4) owns exactly msum for node rnl, cols rq4..+3
#pragma unroll
                for (int h = 0; h < 4; ++h) {
                    int r = rq4 + h;
                    sInT2[r * 32 + (rnl ^ ((r & 7) << 2))] = msum[h];
                }
            }
        }
        __syncthreads();

#pragma unroll
        for (int k = 0; k < 32; ++k) {
            float m = sInT2[k * 32 + (ng2 ^ ((k & 7) << 2))];
            const float* wr = &sBuf[k * 128 + og2 * 16];
            float4 w0 = *(const float4*)&wr[0];
            float4 w1 = *(const float4*)&wr[4];
            float4 w2 = *(const float4*)&wr[8];
            float4 w3 = *(const float4*)&wr[12];
            v2f wp[8] = { {w0.x,w0.y},{w0.z,w0.w},{w1.x,w1.y},{w1.z,w1.w},
                          {w2.x,w2.y},{w2.z,w2.w},{w3.x,w3.y},{w3.z,w3.w} };
#pragma unroll
            for (int h = 0; h < 8; ++h) acc2v[h] += wp[h] * m;
        }
    }

    {
        int n = n0b + ng2;
        if (n < N_NODES) {
            float* dst = out + (size_t)n * F_NODE + og2 * 16;
#pragma unroll
            for (int j = 0; j < 16; j += 4) {
                float4 v;
                v.x = fmaxf(acc2v[(j + 0) >> 1][0] + bn[og2 * 16 + j + 0], 0.f);
                v.y = fmaxf(acc2v[(j + 1) >> 1][1] + bn[og2 * 16 + j + 1], 0.f);
                v.z = fmaxf(acc2v[(j + 2) >> 1][0] + bn[og2 * 16 + j + 2], 0.f);
                v.w = fmaxf(acc2v[(j + 3) >> 1][1] + bn[og2 * 16 + j + 3], 0.f);
                *(float4*)(dst + j) = v;
            }
        }
    }
}

extern "C" void kernel_launch(void* const* d_in, const int* in_sizes, int n_in,
                              void* d_out, int out_size, void* d_ws, size_t ws_size,
                              hipStream_t stream) {
    const float* nf  = (const float*)d_in[0];
    const int*   idx = (const int*)d_in[1];
    const float* ef  = (const float*)d_in[2];
    const float* We  = (const float*)d_in[3];
    const float* be  = (const float*)d_in[4];
    const float* Wn  = (const float*)d_in[5];
    const float* bn  = (const float*)d_in[6];
    float* out = (float*)d_out;

    // ws: deg 0.2 + rank 2.4 + perm 2.4 + Q 3.2 + P0 3.2 = 11.4 MB
    int* deg  = (int*)d_ws;                  // 50000 (counts -> start offsets)
    int* rank = deg + N_NODES;               // 600000
    int* perm = rank + N_EDGES;              // 600000
    unsigned short* Q   = (unsigned short*)(perm + N_EDGES);   // [N][32] bf16
    unsigned short* P0g = Q + (size_t)N_NODES * MSG;           // [N][32] bf16

    hipMemsetAsync(deg, 0, (size_t)N_NODES * sizeof(int), stream);

    hist_kernel<<<QB64 + CBLOCKS, 256, 0, stream>>>(nf, We, be, idx, Q, P0g, deg, rank);
    scan_kernel<<<1, 1024, 0, stream>>>(deg);
    place_kernel<<<CBLOCKS, 256, 0, stream>>>(idx, deg, rank, perm);

    fused_kernel<<<FBLOCKS, 256, 0, stream>>>(
        nf, idx, ef, We, Wn, bn, perm, deg, Q, P0g, out);
}

// Round 6
// 260.299 us; speedup vs baseline: 1.3512x; 1.0447x over previous
//
#include <hip/hip_runtime.h>

#define N_NODES 50000
#define N_EDGES 600000
#define F_NODE 128
#define F_EDGE 32
#define MSG 32
#define NPB 32          // nodes per fused block -> 1563 blocks (6.1/CU)
#define CHK 128         // edges per chunk
#define QB64 ((N_NODES + 63) / 64)                 // 782 (hist GEMM tiles)
#define FBLOCKS ((N_NODES + NPB - 1) / NPB)        // 1563
#define CBLOCKS ((N_EDGES + 255) / 256)            // 2344

typedef float v2f __attribute__((ext_vector_type(2)));   // -> v_pk_fma_f32

// bf16 helpers
__device__ __forceinline__ unsigned short f2bf(float f) {
    union { float f; unsigned int u; } v; v.f = f;
    unsigned int r = v.u + 0x7fffu + ((v.u >> 16) & 1u);
    return (unsigned short)(r >> 16);
}

// Raw barrier: lgkmcnt(0)-only fence + s_barrier (no vmcnt drain ->
// prefetched global loads stay in flight across barriers).
#define BAR_LGKM() do {                                           \
    asm volatile("s_waitcnt lgkmcnt(0)" ::: "memory");            \
    __builtin_amdgcn_s_barrier();                                 \
    asm volatile("" ::: "memory");                                \
} while (0)

// ---------------------------------------------------------------------------
// hist_kernel: blocks [0,QB64): dual node-term GEMM (P0, Q -> bf16).
// Blocks [QB64,..): degree histogram WITH RANK CAPTURE (rank[e] = old count).
// (proven)
// ---------------------------------------------------------------------------
__global__ __launch_bounds__(256)
void hist_kernel(const float* __restrict__ nf,
                 const float* __restrict__ We,     // [288][32]
                 const float* __restrict__ be,     // [32]
                 const int* __restrict__ idx,      // [2][E]
                 unsigned short* __restrict__ Q,   // [N][32] bf16
                 unsigned short* __restrict__ P0g, // [N][32] bf16
                 int* __restrict__ deg,            // [N] counts
                 int* __restrict__ rank)           // [E]
{
    if (blockIdx.x >= QB64) {
        int e = (blockIdx.x - QB64) * 256 + threadIdx.x;
        if (e < N_EDGES) {
            int n = idx[e];
            if ((unsigned)n >= (unsigned)N_NODES) n = 0;
            rank[e] = atomicAdd(&deg[n], 1);
        }
        return;
    }
    __shared__ float sInT[32 * 64];
    __shared__ float sWeA[32 * 32];   // We top (P0 half)
    __shared__ float sWeB[32 * 32];   // We mid (Q half)

    const int tid = threadIdx.x;
    const int n0b = blockIdx.x * 64;
    const int ng = tid & 31;
    const int og = tid >> 5;

    v2f accA[4], accB[4];
#pragma unroll
    for (int j = 0; j < 4; ++j) { accA[j] = (v2f){0.f, 0.f}; accB[j] = (v2f){0.f, 0.f}; }

    for (int kc = 0; kc < 4; ++kc) {
        __syncthreads();
        ((float4*)sWeA)[tid] = ((const float4*)(We + kc * 32 * MSG))[tid];
        ((float4*)sWeB)[tid] = ((const float4*)(We + (128 + kc * 32) * MSG))[tid];
        {
            int nl = tid >> 2, q = tid & 3;
            int n = n0b + nl; if (n >= N_NODES) n = N_NODES - 1;
            const float4* src4 = (const float4*)(nf + (size_t)n * F_NODE + kc * 32);
#pragma unroll
            for (int h = 0; h < 2; ++h) {
                float4 v = src4[q * 2 + h];
                int kl = q * 8 + h * 4;
                sInT[(kl + 0) * 64 + nl] = v.x;
                sInT[(kl + 1) * 64 + nl] = v.y;
                sInT[(kl + 2) * 64 + nl] = v.z;
                sInT[(kl + 3) * 64 + nl] = v.w;
            }
        }
        __syncthreads();
#pragma unroll
        for (int k = 0; k < 32; ++k) {
            v2f m = *(const v2f*)&sInT[k * 64 + 2 * ng];
            float4 wa = *(const float4*)&sWeA[k * 32 + og * 4];
            float4 wb = *(const float4*)&sWeB[k * 32 + og * 4];
            accA[0] += m * wa.x; accA[1] += m * wa.y;
            accA[2] += m * wa.z; accA[3] += m * wa.w;
            accB[0] += m * wb.x; accB[1] += m * wb.y;
            accB[2] += m * wb.z; accB[3] += m * wb.w;
        }
    }
    float bloc[4];
#pragma unroll
    for (int j = 0; j < 4; ++j) bloc[j] = be[og * 4 + j];
#pragma unroll
    for (int i = 0; i < 2; ++i) {
        int n = n0b + 2 * ng + i;
        if (n < N_NODES) {
            ushort4 oq, op;
            oq.x = f2bf(accB[0][i]); oq.y = f2bf(accB[1][i]);
            oq.z = f2bf(accB[2][i]); oq.w = f2bf(accB[3][i]);
            op.x = f2bf(accA[0][i] + bloc[0]); op.y = f2bf(accA[1][i] + bloc[1]);
            op.z = f2bf(accA[2][i] + bloc[2]); op.w = f2bf(accA[3][i] + bloc[3]);
            *(ushort4*)(Q   + (size_t)n * MSG + og * 4) = oq;
            *(ushort4*)(P0g + (size_t)n * MSG + og * 4) = op;
        }
    }
}

// ---------------------------------------------------------------------------
// scan v3 (proven): int4 per thread, in-place exclusive scan counts->starts.
// ---------------------------------------------------------------------------
__global__ __launch_bounds__(1024)
void scan_kernel(int* __restrict__ deg_cursor) {
    __shared__ int wsum[16];
    __shared__ int wpre[16];
    const int t = threadIdx.x;
    const int lane = t & 63;
    const int wid = t >> 6;
    const int N4 = N_NODES / 4;              // 12500
    const int NT = (N4 + 1023) / 1024;       // 13
    int run = 0;
    int4 vnext = make_int4(0, 0, 0, 0);
    if (t < N4) vnext = ((const int4*)deg_cursor)[t];
    for (int tt = 0; tt < NT; ++tt) {
        int4 v = vnext;
        if (tt + 1 < NT) {
            int ni = (tt + 1) * 1024 + t;
            vnext = (ni < N4) ? ((const int4*)deg_cursor)[ni] : make_int4(0, 0, 0, 0);
        }
        int s = v.x + v.y + v.z + v.w;
        int x = s;
#pragma unroll
        for (int d = 1; d < 64; d <<= 1) {
            int u = __shfl_up(x, (unsigned)d, 64);
            if (lane >= d) x += u;
        }
        if (lane == 63) wsum[wid] = x;
        BAR_LGKM();
        if (wid == 0) {
            int ss = (lane < 16) ? wsum[lane] : 0;
#pragma unroll
            for (int d = 1; d < 16; d <<= 1) {
                int u = __shfl_up(ss, (unsigned)d, 64);
                if (lane >= d) ss += u;
            }
            if (lane < 16) wpre[lane] = ss;
        }
        BAR_LGKM();
        int wexcl = (wid > 0) ? wpre[wid - 1] : 0;
        int total = wpre[15];
        int i4 = tt * 1024 + t;
        if (i4 < N4) {
            int base = run + wexcl + (x - s);
            int4 o;
            o.x = base;
            o.y = base + v.x;
            o.z = base + v.x + v.y;
            o.w = base + v.x + v.y + v.z;
            ((int4*)deg_cursor)[i4] = o;
        }
        run += total;
        BAR_LGKM();
    }
}

// ---------------------------------------------------------------------------
// place: perm[start[n] + rank[e]] = e — NO atomics. (proven)
// ---------------------------------------------------------------------------
__global__ void place_kernel(const int* __restrict__ idx,
                             const int* __restrict__ startArr,
                             const int* __restrict__ rank,
                             int* __restrict__ perm) {
    int e = blockIdx.x * 256 + threadIdx.x;
    if (e < N_EDGES) {
        int n = idx[e];
        if ((unsigned)n >= (unsigned)N_NODES) n = 0;
        int p = startArr[n] + rank[e];
        if ((unsigned)p < (unsigned)N_EDGES) perm[p] = e;
    }
}

// ---------------------------------------------------------------------------
// Fused kernel v7 — LDS-pipe + barrier attack (v6 lesson: VALU halving did
// nothing; LDS instr count & 4 barriers/chunk are the critical path).
//  - sBuf (ef^T) and sMsg (msgT) now DISJOINT -> 2 barriers/chunk (was 4).
//  - Edge GEMM re-tiled 4 edges x 4 cols: per k = 1 b128 m + 1 b128 w
//    (was 3 LDS ops). Node GEMM re-tiled 4 nodes x 4 cols: per k = 2 b128
//    (was 5). Per-output k-ascending accumulation preserved everywhere ->
//    bit-identical to v5/v6.
// LDS 39.6 KB -> still 4 blocks/CU (<= 40 KB). __launch_bounds__(256,4).
// LDS map (floats): [0,4096) sBuf | [4096,8192) sMsg | [8192,9216) sWeC
//   | [9216,9728) sP0h(u16) | [9728,9856) sNL (16B-aligned) | [9856..] sOff
// Phase2 overlay: sWn = S[0,4096), sInT2 = S+4096.
// ---------------------------------------------------------------------------
__global__ __launch_bounds__(256, 4)
void fused_kernel(const float* __restrict__ nf,
                  const int* __restrict__ idx,      // [2][E]
                  const float* __restrict__ ef,     // [E][32]
                  const float* __restrict__ We,     // [288][32]
                  const float* __restrict__ Wn,     // [160][128]
                  const float* __restrict__ bn,     // [128]
                  const int* __restrict__ perm,     // [E] sorted edge ids
                  const int* __restrict__ startArr, // [N] start offsets
                  const unsigned short* __restrict__ Q,    // [N][32] bf16
                  const unsigned short* __restrict__ P0g,  // [N][32] bf16
                  float* __restrict__ out)          // [N][128]
{
    __shared__ __align__(16) float S[9892];
    float* sBuf = S;                                  // [32][128] ef^T
    float* sMsg = S + 4096;                           // [32][128] msgT
    float* sWeC = S + 8192;                           // [32][32] We_bot
    unsigned short* sP0h = (unsigned short*)(S + 9216); // [32][32] bf16
    int* sNL  = (int*)(S + 9728);                     // [128] (ln<<20)|n1, 16B-aligned
    int* sOff = (int*)(S + 9856);                     // [33]
    float* sWn   = S;                                 // phase2 Wn tile (overlay)
    float* sInT2 = S + 4096;                          // phase2 nfT/msum (overlay)

    const int tid = threadIdx.x;
    const int n0b = blockIdx.x * NPB;

    if (tid <= NPB) {
        int nn = n0b + tid;
        int v = (nn < N_NODES) ? startArr[nn] : N_EDGES;
        if (v < 0) v = 0;
        if (v > N_EDGES) v = N_EDGES;
        sOff[tid] = v;
    }
    ((float4*)sWeC)[tid] = ((const float4*)(We + 256 * MSG))[tid];  // We_bot
    if (tid < 128) {   // P0 rows for this block's 32 nodes (2 KB coalesced)
        int r = tid >> 2, c = (tid & 3) * 8;
        int n = n0b + r; if (n >= N_NODES) n = N_NODES - 1;
        *(uint4*)(sP0h + r * MSG + c) = *(const uint4*)(P0g + (size_t)n * MSG + c);
    }
    __syncthreads();

    const int rs = sOff[0];
    const int re = sOff[NPB];

    // persistent per-thread message sums: thread = (node rnl, cols rq4..+3)
    float msum[4];
#pragma unroll
    for (int j = 0; j < 4; ++j) msum[j] = 0.f;
    const int rnl = tid >> 3;            // node 0..31
    const int rq4 = (tid & 7) * 4;       // col group
    const int gx  = (rq4 >> 3) << 2;     // reduce-phase swizzle (matches store)

    const int eq = tid & 31;   // GEMM: edges 4eq..4eq+3
    const int cq = tid >> 5;   // GEMM: cols 4cq..4cq+3
    const int g1 = (cq >> 1) & 3;        // store row-group swizzle (const/thread)
    const int el = tid >> 1;   // staged edge slot 0..127
    const int h2 = tid & 1;    // which half of the ef row

    // ---- prefetch pipeline registers -------------------------------------
    int n1r = 0;                     // n1 for chunk i (h2==0 lanes)
    int pe_next = 0, pe_next2 = 0;   // perm for chunk i+1 / in flight i+2
    float4 efr[4];                   // my ef half-row for chunk i
#pragma unroll
    for (int q = 0; q < 4; ++q) efr[q] = make_float4(0.f, 0.f, 0.f, 0.f);

    if (rs < re) {
        int e0 = rs + el;
        int pe0 = 0;
        if (e0 < re) {
            pe0 = perm[e0];
            if ((unsigned)pe0 >= (unsigned)N_EDGES) pe0 = 0;   // poison guard
            if (h2 == 0) {
                int tn = idx[N_EDGES + pe0];
                if ((unsigned)tn >= (unsigned)N_NODES) tn = 0;
                n1r = tn;
            }
        }
        const float4* ef4 = (const float4*)(ef + (size_t)pe0 * F_EDGE + h2 * 16);
#pragma unroll
        for (int q = 0; q < 4; ++q) efr[q] = ef4[q];
        int e1 = rs + CHK + el;
        if (e1 < re) {
            int p = perm[e1];
            if ((unsigned)p >= (unsigned)N_EDGES) p = 0;
            pe_next = p;
        }
        pe_next2 = pe_next;          // bootstrap rotation for iter 0
    }

    // ================= Chunk loop (2 barriers) ============================
    for (int cs = rs; cs < re; cs += CHK) {
        pe_next = pe_next2;
        {
            // ---- stage ef^T(i) into sBuf (k-major, swizzled) ----
#pragma unroll
            for (int q = 0; q < 4; ++q) {
                float4 v = efr[q];
                int g = (h2 * 2 + (q >> 1)) & 3;              // (row>>3)&3 of this quad
                int ctw = ((el & ~3) ^ (g << 2)) + (el & 3);
                int r0 = (h2 * 16 + q * 4) * CHK;
                sBuf[r0 + 0 * CHK + ctw] = v.x;
                sBuf[r0 + 1 * CHK + ctw] = v.y;
                sBuf[r0 + 2 * CHK + ctw] = v.z;
                sBuf[r0 + 3 * CHK + ctw] = v.w;
            }
            // ---- ln (binary search over sOff[0..32]) + packed sNL ----
            if (h2 == 0) {
                int e = cs + el;
                int ln = 0;
                if (e < re) {
                    int lo = 0, hi = NPB;
#pragma unroll
                    for (int s = 0; s < 5; ++s) {
                        int mid = (lo + hi) >> 1;
                        if (sOff[mid] <= e) lo = mid; else hi = mid;
                    }
                    ln = lo;
                }
                sNL[el] = (ln << 20) | n1r;
            }
            // ---- issue gathers for chunk i+1 ----
            int e1 = cs + CHK + el;
            if (e1 < re) {
                int pe1 = pe_next;
                if (h2 == 0) {
                    int tn = idx[N_EDGES + pe1];
                    if ((unsigned)tn >= (unsigned)N_NODES) tn = 0;
                    n1r = tn;
                }
                const float4* ef4 = (const float4*)(ef + (size_t)pe1 * F_EDGE + h2 * 16);
#pragma unroll
                for (int q = 0; q < 4; ++q) efr[q] = ef4[q];
            } else if (h2 == 0) n1r = 0;
            // ---- issue perm for chunk i+2 ----
            int e2 = cs + 2 * CHK + el;
            if (e2 < re) {
                int p = perm[e2];
                if ((unsigned)p >= (unsigned)N_EDGES) p = 0;
                pe_next2 = p;
            } else pe_next2 = 0;
        }
        BAR_LGKM();        // (A) staging visible; prev reduce done (>=1 bar ago)

        // Q gather (4 edges x 4 cols = uint2 each), in flight during GEMM
        int4 nlq = *(const int4*)&sNL[4 * eq];
        int nlv[4] = { nlq.x, nlq.y, nlq.z, nlq.w };
        uint2 qv[4];
#pragma unroll
        for (int i = 0; i < 4; ++i)
            qv[i] = *(const uint2*)(Q + (size_t)(nlv[i] & 0xFFFFF) * MSG + cq * 4);

        v2f accp[4][2];                    // [col j][edge pair p]
#pragma unroll
        for (int j = 0; j < 4; ++j) { accp[j][0] = (v2f){0.f,0.f}; accp[j][1] = (v2f){0.f,0.f}; }

#pragma unroll
        for (int k = 0; k < 32; ++k) {
            float4 m4 = *(const float4*)&sBuf[k * CHK + ((4 * eq) ^ (((k >> 3) & 3) << 2))];
            float4 w  = *(const float4*)&sWeC[k * 32 + cq * 4];
            v2f m01 = (v2f){m4.x, m4.y}, m23 = (v2f){m4.z, m4.w};
            accp[0][0] += m01 * w.x; accp[0][1] += m23 * w.x;
            accp[1][0] += m01 * w.y; accp[1][1] += m23 * w.y;
            accp[2][0] += m01 * w.z; accp[2][1] += m23 * w.z;
            accp[3][0] += m01 * w.w; accp[3][1] += m23 * w.w;
        }

        // ---- +P0 +Q, relu, store msgT[col][edge] (b128 along edges) ----
        {
            uint2 pv[4];
#pragma unroll
            for (int i = 0; i < 4; ++i)
                pv[i] = *(const uint2*)(sP0h + (nlv[i] >> 20) * MSG + cq * 4);
            int sb = (4 * eq) ^ (g1 << 2);
#pragma unroll
            for (int j = 0; j < 4; ++j) {
                float sv[4];
#pragma unroll
                for (int i = 0; i < 4; ++i) {
                    unsigned qu = (j < 2) ? qv[i].x : qv[i].y;
                    unsigned pu = (j < 2) ? pv[i].x : pv[i].y;
                    float qf = __uint_as_float((j & 1) ? (qu & 0xffff0000u) : (qu << 16));
                    float pf = __uint_as_float((j & 1) ? (pu & 0xffff0000u) : (pu << 16));
                    sv[i] = fmaxf(accp[j][i >> 1][i & 1] + pf + qf, 0.f);
                }
                *(float4*)&sMsg[(cq * 4 + j) * CHK + sb] =
                    make_float4(sv[0], sv[1], sv[2], sv[3]);
            }
        }
        BAR_LGKM();        // (B) msgT visible; sBuf reads done (next stage safe)

        // ---- segmented reduction (no atomics): my node's range this chunk
        {
            int lo = sOff[rnl] - cs;     if (lo < 0) lo = 0;
            int hi = sOff[rnl + 1] - cs; if (hi > CHK) hi = CHK;
            for (int elr = lo; elr < hi; ++elr) {
                int ebase = ((elr & ~3) ^ gx) + (elr & 3);
#pragma unroll
                for (int j = 0; j < 4; ++j)
                    msum[j] += sMsg[(rq4 + j) * CHK + ebase];
            }
        }
    }

    // ================= Phase 2: node GEMM, 4 nodes x 4 cols / thread =====
    const int png = tid & 7;       // nodes 4*png..+3
    const int pcg = tid >> 3;      // cols 4*pcg..+3

    v2f acc2[4][2];                // [col j][node pair p]
#pragma unroll
    for (int j = 0; j < 4; ++j) { acc2[j][0] = (v2f){0.f,0.f}; acc2[j][1] = (v2f){0.f,0.f}; }

    for (int kc = 0; kc < 5; ++kc) {
        __syncthreads();   // kc=0: last reduce reads done (full drain ok here)
        {
            const float4* w4 = (const float4*)(Wn + (size_t)kc * 32 * 128);
            float4* s4 = (float4*)sWn;
#pragma unroll
            for (int i = 0; i < 4; ++i) s4[tid + 256 * i] = w4[tid + 256 * i];
        }
        {
            if (kc < 4) {
                int nl = tid >> 3, q = tid & 7;
                int n = n0b + nl; if (n >= N_NODES) n = N_NODES - 1;
                float4 v = *(const float4*)(nf + (size_t)n * F_NODE + kc * 32 + q * 4);
#pragma unroll
                for (int h = 0; h < 4; ++h) {
                    int r = q * 4 + h;
                    sInT2[r * 32 + (nl ^ ((r & 7) << 2))] = (&v.x)[h];
                }
            } else {
                // thread (rnl, rq4) owns exactly msum for node rnl, cols rq4..+3
#pragma unroll
                for (int h = 0; h < 4; ++h) {
                    int r = rq4 + h;
                    sInT2[r * 32 + (rnl ^ ((r & 7) << 2))] = msum[h];
                }
            }
        }
        __syncthreads();

#pragma unroll
        for (int k = 0; k < 32; ++k) {
            float4 m4 = *(const float4*)&sInT2[k * 32 + ((4 * png) ^ ((k & 7) << 2))];
            float4 w  = *(const float4*)&sWn[k * 128 + 4 * pcg];
            v2f m01 = (v2f){m4.x, m4.y}, m23 = (v2f){m4.z, m4.w};
            acc2[0][0] += m01 * w.x; acc2[0][1] += m23 * w.x;
            acc2[1][0] += m01 * w.y; acc2[1][1] += m23 * w.y;
            acc2[2][0] += m01 * w.z; acc2[2][1] += m23 * w.z;
            acc2[3][0] += m01 * w.w; acc2[3][1] += m23 * w.w;
        }
    }

    {
        float4 bnv = *(const float4*)(bn + 4 * pcg);
#pragma unroll
        for (int p = 0; p < 2; ++p)
#pragma unroll
            for (int l = 0; l < 2; ++l) {
                int n = n0b + 4 * png + 2 * p + l;
                if (n < N_NODES) {
                    float4 v;
                    v.x = fmaxf(acc2[0][p][l] + bnv.x, 0.f);
                    v.y = fmaxf(acc2[1][p][l] + bnv.y, 0.f);
                    v.z = fmaxf(acc2[2][p][l] + bnv.z, 0.f);
                    v.w = fmaxf(acc2[3][p][l] + bnv.w, 0.f);
                    *(float4*)(out + (size_t)n * F_NODE + 4 * pcg) = v;
                }
            }
    }
}

extern "C" void kernel_launch(void* const* d_in, const int* in_sizes, int n_in,
                              void* d_out, int out_size, void* d_ws, size_t ws_size,
                              hipStream_t stream) {
    const float* nf  = (const float*)d_in[0];
    const int*   idx = (const int*)d_in[1];
    const float* ef  = (const float*)d_in[2];
    const float* We  = (const float*)d_in[3];
    const float* be  = (const float*)d_in[4];
    const float* Wn  = (const float*)d_in[5];
    const float* bn  = (const float*)d_in[6];
    float* out = (float*)d_out;

    // ws: deg 0.2 + rank 2.4 + perm 2.4 + Q 3.2 + P0 3.2 = 11.4 MB
    int* deg  = (int*)d_ws;                  // 50000 (counts -> start offsets)
    int* rank = deg + N_NODES;               // 600000
    int* perm = rank + N_EDGES;              // 600000
    unsigned short* Q   = (unsigned short*)(perm + N_EDGES);   // [N][32] bf16
    unsigned short* P0g = Q + (size_t)N_NODES * MSG;           // [N][32] bf16

    hipMemsetAsync(deg, 0, (size_t)N_NODES * sizeof(int), stream);

    hist_kernel<<<QB64 + CBLOCKS, 256, 0, stream>>>(nf, We, be, idx, Q, P0g, deg, rank);
    scan_kernel<<<1, 1024, 0, stream>>>(deg);
    place_kernel<<<CBLOCKS, 256, 0, stream>>>(idx, deg, rank, perm);

    fused_kernel<<<FBLOCKS, 256, 0, stream>>>(
        nf, idx, ef, We, Wn, bn, perm, deg, Q, P0g, out);
}